// Round 4
// baseline (47319.968 us; speedup 1.0000x reference)
//
#include <hip/hip_runtime.h>

#define NSAMP 16384
#define NSTEP 32

typedef __attribute__((ext_vector_type(8))) short bf16x8;
typedef __attribute__((ext_vector_type(4))) short short4v;
typedef __attribute__((ext_vector_type(4))) float f32x4;
typedef __attribute__((ext_vector_type(2))) unsigned int uint2v;
typedef __attribute__((ext_vector_type(4))) unsigned int uint4v;

__device__ __forceinline__ unsigned short f2bf(float f) {
    unsigned int u = __float_as_uint(f);
    u += 0x7FFFu + ((u >> 16) & 1u);
    return (unsigned short)(u >> 16);
}
__device__ __forceinline__ float bf2fs(short h) {
    return __uint_as_float(((unsigned int)(unsigned short)h) << 16);
}
__device__ __forceinline__ unsigned int cvtpk(float a, float b) {
    unsigned int r;
    asm("v_cvt_pk_bf16_f32 %0, %1, %2" : "=v"(r) : "v"(a), "v"(b));
    return r;
}
__device__ __forceinline__ float ftanh(float x) {
    float e = __expf(2.0f * x);
    return 1.0f - __fdividef(2.0f, e + 1.0f);
}

// ---------------- prep: pack weights to bf16 in d_ws ----------------
__global__ void prep_kernel(const float* __restrict__ W1, const float* __restrict__ W2,
                            const float* __restrict__ W3, const float* __restrict__ W4,
                            unsigned short* __restrict__ ws) {
    int j = blockIdx.x * blockDim.x + threadIdx.x;   // 0..65535
    if (j < 65536) {
        int e = j & 7, l = (j >> 3) & 63, s = (j >> 9) & 1, ks = (j >> 10) & 7, w = j >> 13;
        int m = (w << 5) + (s << 4) + (l & 15);
        int k = (ks << 5) + ((l >> 4) << 3) + e;
        ws[j]         = f2bf(W2[m * 256 + k]);
        ws[65536 + j] = f2bf(W3[m * 256 + k]);
    }
    if (j < 16384) {
        int i = j >> 8, k = j & 255;
        ws[131072 + j] = f2bf(W1[k * 64 + i]);   // W1T[i][k]
        ws[147456 + j] = f2bf(W4[j]);            // W4[i][k]
        int e = j & 7, l = (j >> 3) & 63, ms = (j >> 9) & 1, ks = (j >> 10) & 1, w = j >> 11;
        int m = (w << 5) + (ms << 4) + (l & 15);
        int i2 = (ks << 5) + ((l >> 4) << 3) + e;
        ws[163840 + j] = f2bf(W1[m * 64 + i2]);  // W1 A-frags (K=64)
    }
}

// ---------------- main persistent-integration kernel ----------------
// one block = TWO samples; 8 waves; W1/W2/W3 mfma A-fragments register-resident.
// XT rows (stride 264): 0-63 tangent^T s0, 64-127 tangent^T s1,
//   128/129 h1 s0/s1, 130/131 h2 s0/s1.

#define ZERO5()                                                              \
    _Pragma("unroll") for (int ms = 0; ms < 2; ++ms)                         \
    _Pragma("unroll") for (int ns = 0; ns < 5; ++ns)                         \
        acc[ms][ns] = (f32x4){0.f, 0.f, 0.f, 0.f};

#define ZERO4()                                                              \
    _Pragma("unroll") for (int ms = 0; ms < 2; ++ms)                         \
    _Pragma("unroll") for (int ns = 0; ns < 4; ++ns)                         \
        acc[ms][ns] = (f32x4){0.f, 0.f, 0.f, 0.f};

#define GEMM_PASS_A(WF, HBASE)                                               \
    __builtin_amdgcn_s_setprio(1);                                           \
    _Pragma("unroll") for (int ks = 0; ks < 8; ++ks) {                       \
        const int kr = (ks << 5) + kband;                                    \
        bf16x8 bfr[5];                                                       \
        _Pragma("unroll") for (int ns = 0; ns < 4; ++ns)                     \
            bfr[ns] = *(const bf16x8*)&XT[((ns << 4) + lm) * 264 + kr];      \
        bfr[4] = *(const bf16x8*)&XT[(HBASE + (lm & 1)) * 264 + kr];         \
        _Pragma("unroll") for (int ms = 0; ms < 2; ++ms)                     \
        _Pragma("unroll") for (int ns = 0; ns < 5; ++ns)                     \
            acc[ms][ns] = __builtin_amdgcn_mfma_f32_16x16x32_bf16(           \
                WF[ks][ms], bfr[ns], acc[ms][ns], 0, 0, 0);                  \
    }                                                                        \
    __builtin_amdgcn_s_setprio(0);

#define GEMM_PASS_B(WF)                                                      \
    __builtin_amdgcn_s_setprio(1);                                           \
    _Pragma("unroll") for (int ks = 0; ks < 8; ++ks) {                       \
        const int kr = (ks << 5) + kband;                                    \
        bf16x8 bfr[4];                                                       \
        _Pragma("unroll") for (int ns = 0; ns < 4; ++ns)                     \
            bfr[ns] = *(const bf16x8*)&XT[(((ns + 4) << 4) + lm) * 264 + kr];\
        _Pragma("unroll") for (int ms = 0; ms < 2; ++ms)                     \
        _Pragma("unroll") for (int ns = 0; ns < 4; ++ns)                     \
            acc[ms][ns] = __builtin_amdgcn_mfma_f32_16x16x32_bf16(           \
                WF[ks][ms], bfr[ns], acc[ms][ns], 0, 0, 0);                  \
    }                                                                        \
    __builtin_amdgcn_s_setprio(0);

// Build one sample's tangent rows (64 rows) into XT starting at ROWBASE.
// Conflict-free mapping: lane's 4 chunks are strided (blk = (tid&7) + 8c),
// so each 8-lane group covers 8 distinct bank quads.
#define BUILD_A1(ROWBASE, DOFF)                                              \
    {                                                                        \
        const int i_ = tid >> 3;                                             \
        const int kb_ = (tid & 7) << 3;                                      \
        _Pragma("unroll") for (int c = 0; c < 4; ++c) {                      \
            const int kk = kb_ + (c << 6);                                   \
            const bf16x8 wv = *(const bf16x8*)&W1T[i_ * 264 + kk];           \
            const float4 d0 = *(const float4*)&dvec1[DOFF + kk];             \
            const float4 d1_ = *(const float4*)&dvec1[DOFF + kk + 4];        \
            uint4v o;                                                        \
            o[0] = cvtpk(bf2fs(wv[0]) * d0.x, bf2fs(wv[1]) * d0.y);          \
            o[1] = cvtpk(bf2fs(wv[2]) * d0.z, bf2fs(wv[3]) * d0.w);          \
            o[2] = cvtpk(bf2fs(wv[4]) * d1_.x, bf2fs(wv[5]) * d1_.y);        \
            o[3] = cvtpk(bf2fs(wv[6]) * d1_.z, bf2fs(wv[7]) * d1_.w);        \
            *(uint4v*)&XT[(ROWBASE + i_) * 264 + kk] = o;                    \
        }                                                                    \
    }

__launch_bounds__(512, 2)
__global__ void cnf_kernel(const float* __restrict__ zin,
                           const float* __restrict__ b1g, const float* __restrict__ b2g,
                           const float* __restrict__ b3g, const float* __restrict__ b4g,
                           const unsigned short* __restrict__ ws,
                           float* __restrict__ out)
{
    __shared__ __align__(16) unsigned short XT[132 * 264];   // 69.7 KB
    __shared__ __align__(16) unsigned short W1T[64 * 264];   // 33.8 KB
    __shared__ __align__(16) unsigned short W4L[64 * 264];   // 33.8 KB
    __shared__ __align__(16) unsigned short ZBT[16 * 72];    // 2.3 KB
    __shared__ __align__(16) float dvec1[2 * 256];
    __shared__ __align__(16) float d2vec[2 * 256];
    __shared__ __align__(16) float d3vec[2 * 256];
    __shared__ __align__(16) float hvec[2 * 256];
    __shared__ __align__(16) float b1l[256], b2l[256], b3l[256], b4l[64];
    __shared__ __align__(16) float zbv[2 * 64];
    __shared__ __align__(16) float kav[2 * 64];
    __shared__ float wredp[16];
    __shared__ float misc[4];   // [0..1]=ka_logp per s, [2..3]=logp per s

    const int tid = threadIdx.x;
    const int w = tid >> 6;
    const int l = tid & 63;
    const int lm = l & 15;
    const int bid = blockIdx.x;
    const int r0 = (w << 5) + ((l >> 4) << 2);
    const int kband = (l >> 4) << 3;
    const float DT = -1.0f / 32.0f;

    // ---- register-resident weight fragments ----
    bf16x8 w2f[8][2], w3f[8][2], w1f[2][2];
    {
        const bf16x8* w2g = (const bf16x8*)ws;
        const bf16x8* w3g = w2g + 8192;
        const bf16x8* w1g = (const bf16x8*)(ws + 163840);
#pragma unroll
        for (int ks = 0; ks < 8; ++ks)
#pragma unroll
            for (int s = 0; s < 2; ++s) {
                int idx = (((w << 3) + ks) * 2 + s) * 64 + l;
                w2f[ks][s] = w2g[idx];
                w3f[ks][s] = w3g[idx];
            }
#pragma unroll
        for (int ks = 0; ks < 2; ++ks)
#pragma unroll
            for (int ms = 0; ms < 2; ++ms)
                w1f[ks][ms] = w1g[(((w << 1) + ks) * 2 + ms) * 64 + l];
    }
    // ---- LDS init ----
    for (int c = tid; c < 2048; c += 512) {
        int i = c >> 5, k0 = (c & 31) << 3;
        *(bf16x8*)&W1T[i * 264 + k0] = *(const bf16x8*)&ws[131072 + i * 256 + k0];
        *(bf16x8*)&W4L[i * 264 + k0] = *(const bf16x8*)&ws[147456 + i * 256 + k0];
    }
    for (int c = 144 + tid; c < 1152; c += 512) ZBT[c] = 0;   // zero rows 2-15
    for (int c = tid; c < 256; c += 512) { b1l[c] = b1g[c]; b2l[c] = b2g[c]; b3l[c] = b3g[c]; }
    if (tid < 128) {
        const int s = tid >> 6, i = tid & 63;
        if (s == 0) b4l[i] = b4g[i];
        float z = zin[(bid * 2 + s) * 64 + i];
        zbv[tid] = z;
        ZBT[s * 72 + i] = f2bf(z);
    }
    if (tid < 2) { misc[tid] = 0.f; misc[2 + tid] = 0.f; }
    __syncthreads();

    for (int it = 0; it < NSTEP * 4; ++it) {
        const int e = it & 3;
        f32x4 acc[2][5];

        // ================ P1: deferred logp + z-MFMA (h1/d1 both samples) ====
        if (it > 0 && tid < 2) {
            const int ep = (it - 1) & 3;
            float div = 0.f;
#pragma unroll
            for (int q = 0; q < 8; ++q) div += wredp[tid * 8 + q];
            const float wgt = (ep == 0 || ep == 3) ? 1.f : 2.f;
            float kl = (ep == 0) ? -div : misc[tid] - wgt * div;
            misc[tid] = kl;
            if (ep == 3) misc[2 + tid] += (DT / 6.0f) * kl;
        }
        {
            f32x4 az[2];
            az[0] = (f32x4){0.f, 0.f, 0.f, 0.f};
            az[1] = (f32x4){0.f, 0.f, 0.f, 0.f};
#pragma unroll
            for (int ks = 0; ks < 2; ++ks) {
                const bf16x8 zf = *(const bf16x8*)&ZBT[lm * 72 + (ks << 5) + kband];
#pragma unroll
                for (int ms = 0; ms < 2; ++ms)
                    az[ms] = __builtin_amdgcn_mfma_f32_16x16x32_bf16(w1f[ks][ms], zf, az[ms], 0, 0, 0);
            }
#pragma unroll
            for (int ms = 0; ms < 2; ++ms) {
                const int rb = r0 + (ms << 4);
                float hh[4], dd[4];
#pragma unroll
                for (int rg = 0; rg < 4; ++rg) {
                    float h = ftanh(az[ms][rg] + b1l[rb + rg]);
                    hh[rg] = h; dd[rg] = 1.f - h * h;
                }
                if (lm < 2) {
                    *(float4*)&dvec1[lm * 256 + rb] = make_float4(dd[0], dd[1], dd[2], dd[3]);
                    uint2v hp; hp[0] = cvtpk(hh[0], hh[1]); hp[1] = cvtpk(hh[2], hh[3]);
                    *(uint2v*)&XT[(128 + lm) * 264 + rb] = hp;
                }
            }
        }
        __syncthreads();

        // ================ P2a: tangent s0 rows ================
        BUILD_A1(0, 0)
        __syncthreads();

        // ================ P3: tangent s1 rows + GEMM1 pass A ================
        BUILD_A1(64, 256)
        ZERO5();
        GEMM_PASS_A(w2f, 128)
        __syncthreads();

        // ================ P4: epi2A + GEMM1 pass B ================
        {
#pragma unroll
            for (int ms = 0; ms < 2; ++ms) {
                const int rb = r0 + (ms << 4);
                float hh[4], dd[4];
#pragma unroll
                for (int rg = 0; rg < 4; ++rg) {
                    float h = ftanh(acc[ms][4][rg] + b2l[rb + rg]);
                    hh[rg] = h; dd[rg] = 1.f - h * h;
                }
                if (lm < 2) {
                    uint2v hp; hp[0] = cvtpk(hh[0], hh[1]); hp[1] = cvtpk(hh[2], hh[3]);
                    *(uint2v*)&XT[(130 + lm) * 264 + rb] = hp;
                    *(float4*)&d2vec[lm * 256 + rb] = make_float4(dd[0], dd[1], dd[2], dd[3]);
                }
            }
#pragma unroll
            for (int ms = 0; ms < 2; ++ms) {
                const int rb = r0 + (ms << 4);
                const float4 ds = *(const float4*)&d2vec[rb];          // sample 0
#pragma unroll
                for (int ns = 0; ns < 4; ++ns) {
                    uint2v o;
                    o[0] = cvtpk(acc[ms][ns][0] * ds.x, acc[ms][ns][1] * ds.y);
                    o[1] = cvtpk(acc[ms][ns][2] * ds.z, acc[ms][ns][3] * ds.w);
                    *(uint2v*)&XT[((ns << 4) + lm) * 264 + rb] = o;
                }
            }
            ZERO4();
            GEMM_PASS_B(w2f)
        }
        __syncthreads();

        // ================ P5: epi2B (A2 s1) + GEMM2 pass A ================
        {
#pragma unroll
            for (int ms = 0; ms < 2; ++ms) {
                const int rb = r0 + (ms << 4);
                const float4 ds = *(const float4*)&d2vec[256 + rb];    // sample 1
#pragma unroll
                for (int ns = 0; ns < 4; ++ns) {
                    uint2v o;
                    o[0] = cvtpk(acc[ms][ns][0] * ds.x, acc[ms][ns][1] * ds.y);
                    o[1] = cvtpk(acc[ms][ns][2] * ds.z, acc[ms][ns][3] * ds.w);
                    *(uint2v*)&XT[(((ns + 4) << 4) + lm) * 264 + rb] = o;
                }
            }
            ZERO5();
            GEMM_PASS_A(w3f, 130)
        }
        __syncthreads();

        // ================ P6: epi3A (h3/d3, div s0) + GEMM2 pass B ================
        float p0 = 0.f;
        {
#pragma unroll
            for (int ms = 0; ms < 2; ++ms) {
                const int rb = r0 + (ms << 4);
                float hh[4], dd[4];
#pragma unroll
                for (int rg = 0; rg < 4; ++rg) {
                    float h = ftanh(acc[ms][4][rg] + b3l[rb + rg]);
                    hh[rg] = h; dd[rg] = 1.f - h * h;
                }
                if (lm < 2) {
                    *(float4*)&hvec[lm * 256 + rb] = make_float4(hh[0], hh[1], hh[2], hh[3]);
                    *(float4*)&d3vec[lm * 256 + rb] = make_float4(dd[0], dd[1], dd[2], dd[3]);
                }
            }
#pragma unroll
            for (int ms = 0; ms < 2; ++ms) {
                const int rb = r0 + (ms << 4);
                const float4 ds = *(const float4*)&d3vec[rb];          // sample 0
#pragma unroll
                for (int ns = 0; ns < 4; ++ns) {
                    const short4v wv = *(const short4v*)&W4L[((ns << 4) + lm) * 264 + rb];
                    p0 += acc[ms][ns][0] * ds.x * bf2fs(wv[0]);
                    p0 += acc[ms][ns][1] * ds.y * bf2fs(wv[1]);
                    p0 += acc[ms][ns][2] * ds.z * bf2fs(wv[2]);
                    p0 += acc[ms][ns][3] * ds.w * bf2fs(wv[3]);
                }
            }
            ZERO4();
            GEMM_PASS_B(w3f)
        }
        __syncthreads();

        // ================ P7: epi3B (div s1) + reduces + dz matvec + RK ======
        {
            float p1 = 0.f;
#pragma unroll
            for (int ms = 0; ms < 2; ++ms) {
                const int rb = r0 + (ms << 4);
                const float4 ds = *(const float4*)&d3vec[256 + rb];    // sample 1
#pragma unroll
                for (int ns = 0; ns < 4; ++ns) {
                    const short4v wv = *(const short4v*)&W4L[((ns << 4) + lm) * 264 + rb];
                    p1 += acc[ms][ns][0] * ds.x * bf2fs(wv[0]);
                    p1 += acc[ms][ns][1] * ds.y * bf2fs(wv[1]);
                    p1 += acc[ms][ns][2] * ds.z * bf2fs(wv[2]);
                    p1 += acc[ms][ns][3] * ds.w * bf2fs(wv[3]);
                }
            }
#pragma unroll
            for (int o = 32; o; o >>= 1) {
                p0 += __shfl_xor(p0, o, 64);
                p1 += __shfl_xor(p1, o, 64);
            }
            if (l == 0) { wredp[w] = p0; wredp[8 + w] = p1; }

            // dz matvec: wave w owns sample s = w>>2, latent dims i0..i0+15
            const int s = w >> 2, i0 = (w & 3) << 4, i = i0 + lm, ch = l >> 4;
            const unsigned short* wr = &W4L[i * 264 + (ch << 6)];
            const float* hv = &hvec[s * 256 + (ch << 6)];
            float a = 0.f;
#pragma unroll
            for (int c = 0; c < 8; ++c) {
                bf16x8 wv = *(const bf16x8*)&wr[c * 8];
                float4 h0 = *(const float4*)&hv[c * 8];
                float4 h1 = *(const float4*)&hv[c * 8 + 4];
                a += bf2fs(wv[0]) * h0.x + bf2fs(wv[1]) * h0.y + bf2fs(wv[2]) * h0.z + bf2fs(wv[3]) * h0.w;
                a += bf2fs(wv[4]) * h1.x + bf2fs(wv[5]) * h1.y + bf2fs(wv[6]) * h1.z + bf2fs(wv[7]) * h1.w;
            }
            a += __shfl_xor(a, 16, 64);
            a += __shfl_xor(a, 32, 64);
            const float dz = a + b4l[i];

            const float wgt = (e == 0 || e == 3) ? 1.f : 2.f;
            const float kv = (e == 0) ? dz : kav[s * 64 + i] + wgt * dz;
            float znew;
            if (e < 3) {
                const float cc = (e == 2) ? 1.0f : 0.5f;
                znew = zbv[s * 64 + i] + cc * DT * dz;
            } else {
                znew = zbv[s * 64 + i] + (DT / 6.0f) * kv;
            }
            if (l < 16) {
                kav[s * 64 + i] = kv;
                if (e == 3) zbv[s * 64 + i] = znew;
                ZBT[s * 72 + i] = f2bf(znew);
            }
        }
        __syncthreads();
    }

    // final deferred logp for it = 127 (e = 3)
    if (tid < 2) {
        float div = 0.f;
#pragma unroll
        for (int q = 0; q < 8; ++q) div += wredp[tid * 8 + q];
        float kl = misc[tid] - div;
        misc[2 + tid] += (DT / 6.0f) * kl;
    }
    __syncthreads();

    if (tid < 128) {
        const int s = tid >> 6, i = tid & 63;
        out[(bid * 2 + s) * 64 + i] = zbv[tid];
        if (i == 0) out[NSAMP * 64 + bid * 2 + s] = misc[2 + s];
    }
}

extern "C" void kernel_launch(void* const* d_in, const int* in_sizes, int n_in,
                              void* d_out, int out_size, void* d_ws, size_t ws_size,
                              hipStream_t stream) {
    const float* z  = (const float*)d_in[0];
    const float* W1 = (const float*)d_in[1];
    const float* b1 = (const float*)d_in[2];
    const float* W2 = (const float*)d_in[3];
    const float* b2 = (const float*)d_in[4];
    const float* W3 = (const float*)d_in[5];
    const float* b3 = (const float*)d_in[6];
    const float* W4 = (const float*)d_in[7];
    const float* b4 = (const float*)d_in[8];
    unsigned short* ws = (unsigned short*)d_ws;
    float* out = (float*)d_out;

    hipLaunchKernelGGL(prep_kernel, dim3(256), dim3(256), 0, stream, W1, W2, W3, W4, ws);
    hipLaunchKernelGGL(cnf_kernel, dim3(NSAMP / 2), dim3(512), 0, stream, z, b1, b2, b3, b4, ws, out);
}

// Round 5
// 42894.455 us; speedup vs baseline: 1.1032x; 1.1032x over previous
//
#include <hip/hip_runtime.h>

#define NSAMP 16384
#define NSTEP 32

typedef __attribute__((ext_vector_type(8))) short bf16x8;
typedef __attribute__((ext_vector_type(4))) short short4v;
typedef __attribute__((ext_vector_type(4))) float f32x4;
typedef __attribute__((ext_vector_type(2))) unsigned int uint2v;
typedef __attribute__((ext_vector_type(4))) unsigned int uint4v;

__device__ __forceinline__ unsigned short f2bf(float f) {
    unsigned int u = __float_as_uint(f);
    u += 0x7FFFu + ((u >> 16) & 1u);
    return (unsigned short)(u >> 16);
}
__device__ __forceinline__ float bf2fs(short h) {
    return __uint_as_float(((unsigned int)(unsigned short)h) << 16);
}
__device__ __forceinline__ unsigned int cvtpk(float a, float b) {
    unsigned int r;
    asm("v_cvt_pk_bf16_f32 %0, %1, %2" : "=v"(r) : "v"(a), "v"(b));
    return r;
}
__device__ __forceinline__ float ftanh(float x) {
    float e = __expf(2.0f * x);
    return 1.0f - __fdividef(2.0f, e + 1.0f);
}

// ---------------- prep: pack weights to bf16 in d_ws ----------------
__global__ void prep_kernel(const float* __restrict__ W1, const float* __restrict__ W2,
                            const float* __restrict__ W3, const float* __restrict__ W4,
                            unsigned short* __restrict__ ws) {
    int j = blockIdx.x * blockDim.x + threadIdx.x;   // 0..65535
    if (j < 65536) {
        int e = j & 7, l = (j >> 3) & 63, s = (j >> 9) & 1, ks = (j >> 10) & 7, w = j >> 13;
        int m = (w << 5) + (s << 4) + (l & 15);
        int k = (ks << 5) + ((l >> 4) << 3) + e;
        ws[j]         = f2bf(W2[m * 256 + k]);
        ws[65536 + j] = f2bf(W3[m * 256 + k]);
    }
    if (j < 16384) {
        int i = j >> 8, k = j & 255;
        ws[131072 + j] = f2bf(W1[k * 64 + i]);   // W1T[i][k]
        ws[147456 + j] = f2bf(W4[j]);            // W4[i][k]
        int e = j & 7, l = (j >> 3) & 63, ms = (j >> 9) & 1, ks = (j >> 10) & 1, w = j >> 11;
        int m = (w << 5) + (ms << 4) + (l & 15);
        int i2 = (ks << 5) + ((l >> 4) << 3) + e;
        ws[163840 + j] = f2bf(W1[m * 64 + i2]);  // W1 A-frags (K=64)
    }
}

// ---------------- main persistent-integration kernel ----------------
// one block = TWO samples; 8 waves; W1/W2/W3 mfma A-fragments register-resident.
// XT rows (stride 264): 0-63 tangent^T s0, 64-127 tangent^T s1,
//   128/129 h1 s0/s1, 130/131 h2 s0/s1.
// Tangent build + A2/A3 epilogue writes are COLUMN-SLICED: wave w owns
// k-columns [32w, 32w+32) — matches its GEMM output rows, so d-vectors and
// epi writes are wave-local (no extra barriers) and bank-conflict-free.

#define ZERO5()                                                              \
    _Pragma("unroll") for (int ms = 0; ms < 2; ++ms)                         \
    _Pragma("unroll") for (int ns = 0; ns < 5; ++ns)                         \
        acc[ms][ns] = (f32x4){0.f, 0.f, 0.f, 0.f};

#define ZERO4()                                                              \
    _Pragma("unroll") for (int ms = 0; ms < 2; ++ms)                         \
    _Pragma("unroll") for (int ns = 0; ns < 4; ++ns)                         \
        acc[ms][ns] = (f32x4){0.f, 0.f, 0.f, 0.f};

#define GEMM_PASS_A(WF, HBASE)                                               \
    __builtin_amdgcn_s_setprio(1);                                           \
    _Pragma("unroll") for (int ks = 0; ks < 8; ++ks) {                       \
        const int kr = (ks << 5) + kband;                                    \
        bf16x8 bfr[5];                                                       \
        _Pragma("unroll") for (int ns = 0; ns < 4; ++ns)                     \
            bfr[ns] = *(const bf16x8*)&XT[((ns << 4) + lm) * 264 + kr];      \
        bfr[4] = *(const bf16x8*)&XT[(HBASE + (lm & 1)) * 264 + kr];         \
        _Pragma("unroll") for (int ms = 0; ms < 2; ++ms)                     \
        _Pragma("unroll") for (int ns = 0; ns < 5; ++ns)                     \
            acc[ms][ns] = __builtin_amdgcn_mfma_f32_16x16x32_bf16(           \
                WF[ks][ms], bfr[ns], acc[ms][ns], 0, 0, 0);                  \
    }                                                                        \
    __builtin_amdgcn_s_setprio(0);

#define GEMM_PASS_B(WF)                                                      \
    __builtin_amdgcn_s_setprio(1);                                           \
    _Pragma("unroll") for (int ks = 0; ks < 8; ++ks) {                       \
        const int kr = (ks << 5) + kband;                                    \
        bf16x8 bfr[4];                                                       \
        _Pragma("unroll") for (int ns = 0; ns < 4; ++ns)                     \
            bfr[ns] = *(const bf16x8*)&XT[(((ns + 4) << 4) + lm) * 264 + kr];\
        _Pragma("unroll") for (int ms = 0; ms < 2; ++ms)                     \
        _Pragma("unroll") for (int ns = 0; ns < 4; ++ns)                     \
            acc[ms][ns] = __builtin_amdgcn_mfma_f32_16x16x32_bf16(           \
                WF[ks][ms], bfr[ns], acc[ms][ns], 0, 0, 0);                  \
    }                                                                        \
    __builtin_amdgcn_s_setprio(0);

// Wave-sliced tangent build for sample S: wave w writes XT[(S*64 + lane)][kcol0..kcol0+31]
// = d1_S[k] * W1T[lane][k]. W1T read + XT write are conflict-free (banks 4*lane+...),
// dvec1 reads are full-wave broadcasts of this wave's own slice.
#define BUILD_SLICE(S)                                                       \
    {                                                                        \
        _Pragma("unroll") for (int c = 0; c < 4; ++c) {                      \
            const int kk = kcol0 + (c << 3);                                 \
            const bf16x8 wv = *(const bf16x8*)&W1T[l * 264 + kk];            \
            const float4 d0 = *(const float4*)&dvec1[(S)*256 + kk];          \
            const float4 d1_ = *(const float4*)&dvec1[(S)*256 + kk + 4];     \
            uint4v o;                                                        \
            o[0] = cvtpk(bf2fs(wv[0]) * d0.x, bf2fs(wv[1]) * d0.y);          \
            o[1] = cvtpk(bf2fs(wv[2]) * d0.z, bf2fs(wv[3]) * d0.w);          \
            o[2] = cvtpk(bf2fs(wv[4]) * d1_.x, bf2fs(wv[5]) * d1_.y);        \
            o[3] = cvtpk(bf2fs(wv[6]) * d1_.z, bf2fs(wv[7]) * d1_.w);        \
            *(uint4v*)&XT[((S)*64 + l) * 264 + kk] = o;                      \
        }                                                                    \
    }

__launch_bounds__(512, 2)
__global__ void cnf_kernel(const float* __restrict__ zin,
                           const float* __restrict__ b1g, const float* __restrict__ b2g,
                           const float* __restrict__ b3g, const float* __restrict__ b4g,
                           const unsigned short* __restrict__ ws,
                           float* __restrict__ out)
{
    __shared__ __align__(16) unsigned short XT[132 * 264];   // 69.7 KB
    __shared__ __align__(16) unsigned short W1T[64 * 264];   // 33.8 KB
    __shared__ __align__(16) unsigned short W4L[64 * 264];   // 33.8 KB
    __shared__ __align__(16) unsigned short ZBT[16 * 72];    // 2.3 KB
    __shared__ __align__(16) float dvec1[2 * 256];
    __shared__ __align__(16) float d2vec[2 * 256];
    __shared__ __align__(16) float d3vec[2 * 256];
    __shared__ __align__(16) float hvec[2 * 256];
    __shared__ __align__(16) float b1l[256], b2l[256], b3l[256], b4l[64];
    __shared__ __align__(16) float zbv[2 * 64];
    __shared__ __align__(16) float kav[2 * 64];
    __shared__ float wredp[16];
    __shared__ float misc[4];   // [0..1]=ka_logp per s, [2..3]=logp per s

    const int tid = threadIdx.x;
    const int w = tid >> 6;
    const int l = tid & 63;
    const int lm = l & 15;
    const int bid = blockIdx.x;
    const int r0 = (w << 5) + ((l >> 4) << 2);
    const int kband = (l >> 4) << 3;
    const int kcol0 = w << 5;
    const float DT = -1.0f / 32.0f;

    // ---- register-resident weight fragments ----
    bf16x8 w2f[8][2], w3f[8][2], w1f[2][2];
    {
        const bf16x8* w2g = (const bf16x8*)ws;
        const bf16x8* w3g = w2g + 8192;
        const bf16x8* w1g = (const bf16x8*)(ws + 163840);
#pragma unroll
        for (int ks = 0; ks < 8; ++ks)
#pragma unroll
            for (int s = 0; s < 2; ++s) {
                int idx = (((w << 3) + ks) * 2 + s) * 64 + l;
                w2f[ks][s] = w2g[idx];
                w3f[ks][s] = w3g[idx];
            }
#pragma unroll
        for (int ks = 0; ks < 2; ++ks)
#pragma unroll
            for (int ms = 0; ms < 2; ++ms)
                w1f[ks][ms] = w1g[(((w << 1) + ks) * 2 + ms) * 64 + l];
    }
    // ---- LDS init ----
    for (int c = tid; c < 2048; c += 512) {
        int i = c >> 5, k0 = (c & 31) << 3;
        *(bf16x8*)&W1T[i * 264 + k0] = *(const bf16x8*)&ws[131072 + i * 256 + k0];
        *(bf16x8*)&W4L[i * 264 + k0] = *(const bf16x8*)&ws[147456 + i * 256 + k0];
    }
    for (int c = 144 + tid; c < 1152; c += 512) ZBT[c] = 0;   // zero rows 2-15
    for (int c = tid; c < 256; c += 512) { b1l[c] = b1g[c]; b2l[c] = b2g[c]; b3l[c] = b3g[c]; }
    if (tid < 128) {
        const int s = tid >> 6, i = tid & 63;
        if (s == 0) b4l[i] = b4g[i];
        float z = zin[(bid * 2 + s) * 64 + i];
        zbv[tid] = z;
        ZBT[s * 72 + i] = f2bf(z);
    }
    if (tid < 2) { misc[tid] = 0.f; misc[2 + tid] = 0.f; }
    __syncthreads();

    for (int it = 0; it < NSTEP * 4; ++it) {
        const int e = it & 3;
        f32x4 acc[2][5];

        // ======== P1: deferred logp + z-MFMA (h1/d1) + tangent build s0 ======
        if (it > 0 && tid < 2) {
            const int ep = (it - 1) & 3;
            float div = 0.f;
#pragma unroll
            for (int q = 0; q < 8; ++q) div += wredp[tid * 8 + q];
            const float wgt = (ep == 0 || ep == 3) ? 1.f : 2.f;
            float kl = (ep == 0) ? -div : misc[tid] - wgt * div;
            misc[tid] = kl;
            if (ep == 3) misc[2 + tid] += (DT / 6.0f) * kl;
        }
        {
            f32x4 az[2];
            az[0] = (f32x4){0.f, 0.f, 0.f, 0.f};
            az[1] = (f32x4){0.f, 0.f, 0.f, 0.f};
#pragma unroll
            for (int ks = 0; ks < 2; ++ks) {
                const bf16x8 zf = *(const bf16x8*)&ZBT[lm * 72 + (ks << 5) + kband];
#pragma unroll
                for (int ms = 0; ms < 2; ++ms)
                    az[ms] = __builtin_amdgcn_mfma_f32_16x16x32_bf16(w1f[ks][ms], zf, az[ms], 0, 0, 0);
            }
#pragma unroll
            for (int ms = 0; ms < 2; ++ms) {
                const int rb = r0 + (ms << 4);
                float hh[4], dd[4];
#pragma unroll
                for (int rg = 0; rg < 4; ++rg) {
                    float h = ftanh(az[ms][rg] + b1l[rb + rg]);
                    hh[rg] = h; dd[rg] = 1.f - h * h;
                }
                if (lm < 2) {
                    *(float4*)&dvec1[lm * 256 + rb] = make_float4(dd[0], dd[1], dd[2], dd[3]);
                    uint2v hp; hp[0] = cvtpk(hh[0], hh[1]); hp[1] = cvtpk(hh[2], hh[3]);
                    *(uint2v*)&XT[(128 + lm) * 264 + rb] = hp;
                }
            }
        }
        // wave-local: dvec1 slice [kcol0,kcol0+32) written by THIS wave above
        BUILD_SLICE(0)
        __syncthreads();

        // ======== P2: tangent build s1 + GEMM1 pass A ========
        BUILD_SLICE(1)
        ZERO5();
        GEMM_PASS_A(w2f, 128)
        __syncthreads();

        // ======== P3: epi2A (h2/d2, A2 s0 slice) + GEMM1 pass B ========
        {
#pragma unroll
            for (int ms = 0; ms < 2; ++ms) {
                const int rb = r0 + (ms << 4);
                float hh[4], dd[4];
#pragma unroll
                for (int rg = 0; rg < 4; ++rg) {
                    float h = ftanh(acc[ms][4][rg] + b2l[rb + rg]);
                    hh[rg] = h; dd[rg] = 1.f - h * h;
                }
                if (lm < 2) {
                    uint2v hp; hp[0] = cvtpk(hh[0], hh[1]); hp[1] = cvtpk(hh[2], hh[3]);
                    *(uint2v*)&XT[(130 + lm) * 264 + rb] = hp;
                    *(float4*)&d2vec[lm * 256 + rb] = make_float4(dd[0], dd[1], dd[2], dd[3]);
                }
            }
#pragma unroll
            for (int ms = 0; ms < 2; ++ms) {
                const int rb = r0 + (ms << 4);
                const float4 ds = *(const float4*)&d2vec[rb];          // sample 0 (own rows)
#pragma unroll
                for (int ns = 0; ns < 4; ++ns) {
                    uint2v o;
                    o[0] = cvtpk(acc[ms][ns][0] * ds.x, acc[ms][ns][1] * ds.y);
                    o[1] = cvtpk(acc[ms][ns][2] * ds.z, acc[ms][ns][3] * ds.w);
                    *(uint2v*)&XT[((ns << 4) + lm) * 264 + rb] = o;
                }
            }
            ZERO4();
            GEMM_PASS_B(w2f)
        }
        __syncthreads();

        // ======== P4: epi2B (A2 s1 slice) + GEMM2 pass A ========
        {
#pragma unroll
            for (int ms = 0; ms < 2; ++ms) {
                const int rb = r0 + (ms << 4);
                const float4 ds = *(const float4*)&d2vec[256 + rb];    // sample 1 (own rows)
#pragma unroll
                for (int ns = 0; ns < 4; ++ns) {
                    uint2v o;
                    o[0] = cvtpk(acc[ms][ns][0] * ds.x, acc[ms][ns][1] * ds.y);
                    o[1] = cvtpk(acc[ms][ns][2] * ds.z, acc[ms][ns][3] * ds.w);
                    *(uint2v*)&XT[(((ns + 4) << 4) + lm) * 264 + rb] = o;
                }
            }
            ZERO5();
            GEMM_PASS_A(w3f, 130)
        }
        __syncthreads();

        // ======== P5: epi3A (h3/d3, div partial s0) + GEMM2 pass B ========
        float p0 = 0.f;
        {
#pragma unroll
            for (int ms = 0; ms < 2; ++ms) {
                const int rb = r0 + (ms << 4);
                float hh[4], dd[4];
#pragma unroll
                for (int rg = 0; rg < 4; ++rg) {
                    float h = ftanh(acc[ms][4][rg] + b3l[rb + rg]);
                    hh[rg] = h; dd[rg] = 1.f - h * h;
                }
                if (lm < 2) {
                    *(float4*)&hvec[lm * 256 + rb] = make_float4(hh[0], hh[1], hh[2], hh[3]);
                    *(float4*)&d3vec[lm * 256 + rb] = make_float4(dd[0], dd[1], dd[2], dd[3]);
                }
            }
#pragma unroll
            for (int ms = 0; ms < 2; ++ms) {
                const int rb = r0 + (ms << 4);
                const float4 ds = *(const float4*)&d3vec[rb];          // sample 0 (own rows)
#pragma unroll
                for (int ns = 0; ns < 4; ++ns) {
                    const short4v wv = *(const short4v*)&W4L[((ns << 4) + lm) * 264 + rb];
                    p0 += acc[ms][ns][0] * ds.x * bf2fs(wv[0]);
                    p0 += acc[ms][ns][1] * ds.y * bf2fs(wv[1]);
                    p0 += acc[ms][ns][2] * ds.z * bf2fs(wv[2]);
                    p0 += acc[ms][ns][3] * ds.w * bf2fs(wv[3]);
                }
            }
            ZERO4();
            GEMM_PASS_B(w3f)
        }
        __syncthreads();

        // ======== P6: epi3B (div s1) + reduces + dz matvec + RK ========
        {
            float p1 = 0.f;
#pragma unroll
            for (int ms = 0; ms < 2; ++ms) {
                const int rb = r0 + (ms << 4);
                const float4 ds = *(const float4*)&d3vec[256 + rb];    // sample 1 (own rows)
#pragma unroll
                for (int ns = 0; ns < 4; ++ns) {
                    const short4v wv = *(const short4v*)&W4L[((ns << 4) + lm) * 264 + rb];
                    p1 += acc[ms][ns][0] * ds.x * bf2fs(wv[0]);
                    p1 += acc[ms][ns][1] * ds.y * bf2fs(wv[1]);
                    p1 += acc[ms][ns][2] * ds.z * bf2fs(wv[2]);
                    p1 += acc[ms][ns][3] * ds.w * bf2fs(wv[3]);
                }
            }
#pragma unroll
            for (int o = 32; o; o >>= 1) {
                p0 += __shfl_xor(p0, o, 64);
                p1 += __shfl_xor(p1, o, 64);
            }
            if (l == 0) { wredp[w] = p0; wredp[8 + w] = p1; }

            // dz matvec: wave w owns sample s = w>>2, latent dims i0..i0+15
            const int s = w >> 2, i0 = (w & 3) << 4, i = i0 + lm, ch = l >> 4;
            const unsigned short* wr = &W4L[i * 264 + (ch << 6)];
            const float* hv = &hvec[s * 256 + (ch << 6)];
            float a = 0.f;
#pragma unroll
            for (int c = 0; c < 8; ++c) {
                bf16x8 wv = *(const bf16x8*)&wr[c * 8];
                float4 h0 = *(const float4*)&hv[c * 8];
                float4 h1 = *(const float4*)&hv[c * 8 + 4];
                a += bf2fs(wv[0]) * h0.x + bf2fs(wv[1]) * h0.y + bf2fs(wv[2]) * h0.z + bf2fs(wv[3]) * h0.w;
                a += bf2fs(wv[4]) * h1.x + bf2fs(wv[5]) * h1.y + bf2fs(wv[6]) * h1.z + bf2fs(wv[7]) * h1.w;
            }
            a += __shfl_xor(a, 16, 64);
            a += __shfl_xor(a, 32, 64);
            const float dz = a + b4l[i];

            const float wgt = (e == 0 || e == 3) ? 1.f : 2.f;
            const float kv = (e == 0) ? dz : kav[s * 64 + i] + wgt * dz;
            float znew;
            if (e < 3) {
                const float cc = (e == 2) ? 1.0f : 0.5f;
                znew = zbv[s * 64 + i] + cc * DT * dz;
            } else {
                znew = zbv[s * 64 + i] + (DT / 6.0f) * kv;
            }
            if (l < 16) {
                kav[s * 64 + i] = kv;
                if (e == 3) zbv[s * 64 + i] = znew;
                ZBT[s * 72 + i] = f2bf(znew);
            }
        }
        __syncthreads();
    }

    // final deferred logp for it = 127 (e = 3)
    if (tid < 2) {
        float div = 0.f;
#pragma unroll
        for (int q = 0; q < 8; ++q) div += wredp[tid * 8 + q];
        float kl = misc[tid] - div;
        misc[2 + tid] += (DT / 6.0f) * kl;
    }
    __syncthreads();

    if (tid < 128) {
        const int s = tid >> 6, i = tid & 63;
        out[(bid * 2 + s) * 64 + i] = zbv[tid];
        if (i == 0) out[NSAMP * 64 + bid * 2 + s] = misc[2 + s];
    }
}

extern "C" void kernel_launch(void* const* d_in, const int* in_sizes, int n_in,
                              void* d_out, int out_size, void* d_ws, size_t ws_size,
                              hipStream_t stream) {
    const float* z  = (const float*)d_in[0];
    const float* W1 = (const float*)d_in[1];
    const float* b1 = (const float*)d_in[2];
    const float* W2 = (const float*)d_in[3];
    const float* b2 = (const float*)d_in[4];
    const float* W3 = (const float*)d_in[5];
    const float* b3 = (const float*)d_in[6];
    const float* W4 = (const float*)d_in[7];
    const float* b4 = (const float*)d_in[8];
    unsigned short* ws = (unsigned short*)d_ws;
    float* out = (float*)d_out;

    hipLaunchKernelGGL(prep_kernel, dim3(256), dim3(256), 0, stream, W1, W2, W3, W4, ws);
    hipLaunchKernelGGL(cnf_kernel, dim3(NSAMP / 2), dim3(512), 0, stream, z, b1, b2, b3, b4, ws, out);
}